// Round 11
// baseline (4149.421 us; speedup 1.0000x reference)
//
#include <hip/hip_runtime.h>

#define B_ 64
#define T_ 2048
#define F_ 8
#define H_ 128
#define RING_LD 68   // 64 dwords + 4 pad per ring slot

typedef _Float16 v2h   __attribute__((ext_vector_type(2)));
typedef _Float16 f16x8 __attribute__((ext_vector_type(8)));
typedef float    f32x4 __attribute__((ext_vector_type(4)));

__device__ __forceinline__ unsigned pk2h(float lo, float hi) {
    v2h p;
    p[0] = (_Float16)lo;
    p[1] = (_Float16)hi;
    return __builtin_bit_cast(unsigned, p);
}

#if __has_builtin(__builtin_amdgcn_fdot2)
__device__ __forceinline__ float fdot2a(unsigned a, unsigned b, float c) {
    return __builtin_amdgcn_fdot2(__builtin_bit_cast(v2h, a),
                                  __builtin_bit_cast(v2h, b), c, false);
}
#else
__device__ __forceinline__ float fdot2a(unsigned a, unsigned b, float c) {
    v2h av = __builtin_bit_cast(v2h, a);
    v2h bv = __builtin_bit_cast(v2h, b);
    c += (float)av[0] * (float)bv[0];
    c += (float)av[1] * (float)bv[1];
    return c;
}
#endif

__device__ __forceinline__ float sigm(float x) {
    return 1.0f / (1.0f + __expf(-x));
}
__device__ __forceinline__ float tanh_f(float x) {
    float e = __expf(2.0f * x);
    return 1.0f - 2.0f / (e + 1.0f);
}

__device__ __forceinline__ f32x4 mfma16(f16x8 a, f16x8 b, f32x4 c) {
    return __builtin_amdgcn_mfma_f32_16x16x32_f16(a, b, c, 0, 0, 0);
}

// In-quad lane exchanges via DPP quad_perm (VALU pipe, no LDS)
#if __has_builtin(__builtin_amdgcn_mov_dpp)
template <int CTRL>
__device__ __forceinline__ float qperm(float v) {
    int i = __builtin_bit_cast(int, v);
    i = __builtin_amdgcn_mov_dpp(i, CTRL, 0xF, 0xF, true);
    return __builtin_bit_cast(float, i);
}
__device__ __forceinline__ float lane_xor1(float v) { return qperm<0xB1>(v); } // [1,0,3,2]
__device__ __forceinline__ float lane_xor2(float v) { return qperm<0x4E>(v); } // [2,3,0,1]
#else
__device__ __forceinline__ float lane_xor1(float v) {
    int i = __builtin_amdgcn_ds_swizzle(__builtin_bit_cast(int, v), 0x041F);
    return __builtin_bit_cast(float, i);
}
__device__ __forceinline__ float lane_xor2(float v) {
    int i = __builtin_amdgcn_ds_swizzle(__builtin_bit_cast(int, v), 0x081F);
    return __builtin_bit_cast(float, i);
}
#endif

// ---------------------------------------------------------------------------
// HYBRID (round-11): r5 chassis (best verified, 3162us) with per-phase engine
// matched to operand residency so NO register-class copies remain:
//   Phase A (L0): fdot2, weights rwih0[4]+rwhh0[64] = 68 dwords -> fit the
//     128 arch-VGPR cap entirely (plus ~50 temps). Quad-mapped cell update
//     (verified bit-identical since r2).
//   Phase B (L1): r7-verified MFMA broadcast formulation; wih1f+whh1f =
//     32 frags = EXACTLY 128 dwords pinned "+a" (the AGPR half; MFMA reads
//     AGPR B natively, r8-proven). Per-lane activations, no exchanges.
// 2 barriers/tick; h1 in 64-slot padded ring; 64-tick OUT burst (r5).
// Register audit/wave: arch ~120/128, AGPR 128/128 -> zero forced movs.
// ---------------------------------------------------------------------------
__global__ __launch_bounds__(512, 2)
void lstm2_hybrid_kernel(const float* __restrict__ x,
                         const float* __restrict__ wih0,
                         const float* __restrict__ whh0,
                         const float* __restrict__ bih0,
                         const float* __restrict__ bhh0,
                         const float* __restrict__ wih1,
                         const float* __restrict__ whh1,
                         const float* __restrict__ bih1,
                         const float* __restrict__ bhh1,
                         const float* __restrict__ wlin,
                         const float* __restrict__ blin,
                         float* __restrict__ out)
{
    __shared__ __align__(16) unsigned x_lds[T_ * F_ / 2];     // 32 KB packed f16 x
    __shared__ __align__(16) unsigned h0_lds[2][H_ / 2];      // double-buffered h0
    __shared__ __align__(16) unsigned h1_ring[64 * RING_LD];  // 64-tick h1 ring (17 KB)
    __shared__ __align__(16) unsigned wlin_p[F_ * RING_LD];   // w_lin rows, padded
    __shared__ float blin_f[F_];

    const int tid = threadIdx.x;
    const int b   = blockIdx.x;

    // phase-A mapping (fdot2): tid = h_idx*4 + sub, gate order [i,g,f,o]
    const int h_idx = tid >> 2;
    const int sub   = tid & 3;
    const int growA = (0x3120 >> (sub * 4)) & 0xF;      // {0,2,1,3}[sub]
    const int rowA  = growA * H_ + h_idx;

    // phase-B mapping (MFMA): wave w covers rows j*128 + w*16 + n
    const int w   = tid >> 6;     // wave 0..7
    const int l   = tid & 63;     // lane
    const int n   = l & 15;       // fragment column
    const int grp = l >> 4;       // k-slice group 0..3

    // ---- stage x[b] into LDS as packed f16 pairs ----
    const float4* xp = (const float4*)(x + (size_t)b * T_ * F_);
    #pragma unroll
    for (int i = 0; i < 8; ++i) {
        int idx = tid + i * 512;
        float4 v = xp[idx];
        x_lds[idx * 2 + 0] = pk2h(v.x, v.y);
        x_lds[idx * 2 + 1] = pk2h(v.z, v.w);
    }

    // ---- phase-A weights (68 dwords, arch VGPR) ----
    unsigned rwih0[4];
    {
        const float4* p = (const float4*)(wih0 + (size_t)rowA * F_);
        float4 v0 = p[0], v1 = p[1];
        rwih0[0] = pk2h(v0.x, v0.y); rwih0[1] = pk2h(v0.z, v0.w);
        rwih0[2] = pk2h(v1.x, v1.y); rwih0[3] = pk2h(v1.z, v1.w);
    }
    unsigned rwhh0[64];
    {
        const float4* p = (const float4*)(whh0 + (size_t)rowA * H_);
        #pragma unroll
        for (int i = 0; i < 32; ++i) {
            float4 v = p[i];
            rwhh0[i * 2 + 0] = pk2h(v.x, v.y);
            rwhh0[i * 2 + 1] = pk2h(v.z, v.w);
        }
    }
    const float bias0 = bih0[rowA] + bhh0[rowA];

    // ---- phase-B weights as B-frags, pinned AGPR (exactly 128 dwords) ----
    // frag [j][s]: elem jj = W[j*128 + w*16 + n][s*32 + grp*8 + jj]
    f16x8 wih1f[4][4], whh1f[4][4];
    #pragma unroll
    for (int j = 0; j < 4; ++j) {
        const int row = j * H_ + w * 16 + n;
        #pragma unroll
        for (int s = 0; s < 4; ++s) {
            const float* p1 = wih1 + (size_t)row * H_ + s * 32 + grp * 8;
            const float* p2 = whh1 + (size_t)row * H_ + s * 32 + grp * 8;
            f16x8 f1, f2;
            #pragma unroll
            for (int jj = 0; jj < 8; ++jj) {
                f1[jj] = (_Float16)p1[jj];
                f2[jj] = (_Float16)p2[jj];
            }
            wih1f[j][s] = f1;
            whh1f[j][s] = f2;
        }
    }
    #pragma unroll
    for (int j = 0; j < 4; ++j)
        #pragma unroll
        for (int s = 0; s < 4; ++s) {
            asm("" : "+a"(wih1f[j][s]));
            asm("" : "+a"(whh1f[j][s]));
        }

    // phase-B biases (4 regs)
    float bb1[4];
    #pragma unroll
    for (int j = 0; j < 4; ++j) {
        const int row = j * H_ + w * 16 + n;
        bb1[j] = bih1[row] + bhh1[row];
    }

    // w_lin -> padded LDS rows (OUT burst)
    {
        float2 v = ((const float2*)wlin)[tid];
        wlin_p[(tid >> 6) * RING_LD + (tid & 63)] = pk2h(v.x, v.y);
    }
    if (tid < F_) blin_f[tid] = blin[tid];
    if (tid < H_ / 2) {
        h0_lds[0][tid] = 0u; h0_lds[1][tid] = 0u;
        h1_ring[63 * RING_LD + tid] = 0u;   // h1(-1) = 0
    }
    __syncthreads();

    const bool is_g = (sub == 1);
    const bool lo2  = (sub < 2);
    float c0 = 0.0f, c1 = 0.0f;
    const f32x4 Z4 = {0.0f, 0.0f, 0.0f, 0.0f};

    for (int t = 0; t < T_; ++t) {
        const int rp = (t + 1) & 1;   // parity holding h0(t-1)
        const int wp = t & 1;         // parity receiving h0(t)

        // ---------- phase A: layer 0 via fdot2 (weights all arch-VGPR) ----------
        {
            float aa = bias0, ab = 0.0f;
            uint4 xv = *(const uint4*)&x_lds[t * 4];
            aa = fdot2a(rwih0[0], xv.x, aa);
            ab = fdot2a(rwih0[1], xv.y, ab);
            aa = fdot2a(rwih0[2], xv.z, aa);
            ab = fdot2a(rwih0[3], xv.w, ab);
            const unsigned* hr = &h0_lds[rp][0];            // h0(t-1)
            #pragma unroll
            for (int j = 0; j < 16; ++j) {
                uint4 hv = *(const uint4*)&hr[j * 4];
                aa = fdot2a(rwhh0[j * 4 + 0], hv.x, aa);
                ab = fdot2a(rwhh0[j * 4 + 1], hv.y, ab);
                aa = fdot2a(rwhh0[j * 4 + 2], hv.z, aa);
                ab = fdot2a(rwhh0[j * 4 + 3], hv.w, ab);
            }
            float a = aa + ab;
            float xin = is_g ? 2.0f * a : a;
            float s   = sigm(xin);
            float act = is_g ? 2.0f * s - 1.0f : s;        // tanh via sigmoid
            float s1  = lane_xor1(act);
            float p   = lo2 ? act * s1 : (sub == 2 ? act : s1) * c0;
            float cn  = p + lane_xor2(p);
            c0 = cn;
            float oval = (sub == 2) ? s1 : act;
            float h = oval * tanh_f(cn);
            if (sub == 2) ((_Float16*)&h0_lds[wp][0])[h_idx] = (_Float16)h;  // h0(t)
        }

        __syncthreads();   // h0(t) visible

        // ---------- phase B: layer 1 via MFMA (weights all AGPR, read natively) ----------
        {
            const unsigned* h0r = &h0_lds[wp][0];                       // h0(t)
            const unsigned* h1r = &h1_ring[((t + 63) & 63) * RING_LD];  // h1(t-1)
            f32x4 acc[4];
            {
                f16x8 ah = __builtin_bit_cast(f16x8, *(const uint4*)&h0r[grp * 4]);
                #pragma unroll
                for (int j = 0; j < 4; ++j) acc[j] = mfma16(ah, wih1f[j][0], Z4);
            }
            #pragma unroll
            for (int s = 1; s < 4; ++s) {
                f16x8 ah = __builtin_bit_cast(f16x8, *(const uint4*)&h0r[s * 16 + grp * 4]);
                #pragma unroll
                for (int j = 0; j < 4; ++j) acc[j] = mfma16(ah, wih1f[j][s], acc[j]);
            }
            #pragma unroll
            for (int s = 0; s < 4; ++s) {
                f16x8 ah = __builtin_bit_cast(f16x8, *(const uint4*)&h1r[s * 16 + grp * 4]);
                #pragma unroll
                for (int j = 0; j < 4; ++j) acc[j] = mfma16(ah, whh1f[j][s], acc[j]);
            }
            // D row-replicated: reg 0 = gate j of h (w*16 + n)
            float gi = sigm(acc[0][0] + bb1[0]);
            float gf = sigm(acc[1][0] + bb1[1]);
            float gg = tanh_f(acc[2][0] + bb1[2]);
            float go = sigm(acc[3][0] + bb1[3]);
            c1 = gf * c1 + gi * gg;
            float hh = go * tanh_f(c1);
            if (l < 16)
                ((_Float16*)&h1_ring[(t & 63) * RING_LD])[w * 16 + l] = (_Float16)hh;
        }

        __syncthreads();   // h1(t) + ring slot visible

        // ---------- OUT burst: every 64 ticks, 512 outputs in parallel ----------
        if ((t & 63) == 63) {
            const int tick_i = tid >> 3;   // ring slot == tick (t-63+tick_i)
            const int fo     = tid & 7;    // output feature
            const unsigned* hp = &h1_ring[tick_i * RING_LD];
            const unsigned* wv = &wlin_p[fo * RING_LD];
            float a = 0.0f;
            #pragma unroll
            for (int j = 0; j < 16; ++j) {
                uint4 hv = *(const uint4*)&hp[j * 4];
                uint4 wq = *(const uint4*)&wv[j * 4];
                a = fdot2a(wq.x, hv.x, a);
                a = fdot2a(wq.y, hv.y, a);
                a = fdot2a(wq.z, hv.z, a);
                a = fdot2a(wq.w, hv.w, a);
            }
            // tid-consecutive -> address-consecutive: coalesced 2 KB store
            out[(size_t)b * T_ * F_ + (size_t)(t - 63) * F_ + tid] = a + blin_f[fo];
            // store drains at the next phase-A barrier (once per 64 ticks)
        }
    }
}

extern "C" void kernel_launch(void* const* d_in, const int* in_sizes, int n_in,
                              void* d_out, int out_size, void* d_ws, size_t ws_size,
                              hipStream_t stream) {
    const float* x    = (const float*)d_in[0];
    const float* wih0 = (const float*)d_in[1];
    const float* whh0 = (const float*)d_in[2];
    const float* bih0 = (const float*)d_in[3];
    const float* bhh0 = (const float*)d_in[4];
    const float* wih1 = (const float*)d_in[5];
    const float* whh1 = (const float*)d_in[6];
    const float* bih1 = (const float*)d_in[7];
    const float* bhh1 = (const float*)d_in[8];
    const float* wlin = (const float*)d_in[9];
    const float* blin = (const float*)d_in[10];
    float* out = (float*)d_out;

    lstm2_hybrid_kernel<<<dim3(B_), dim3(512), 0, stream>>>(
        x, wih0, whh0, bih0, bhh0, wih1, whh1, bih1, bhh1, wlin, blin, out);
}

// Round 12
// 1808.382 us; speedup vs baseline: 2.2945x; 2.2945x over previous
//
#include <hip/hip_runtime.h>

#define B_ 64
#define T_ 2048
#define F_ 8
#define H_ 128
#define RING_LD 68     // padded row for OUT-burst reads
#define CHUNK 64
#define NCH (T_ / CHUNK)   // 32 chunks
#define GRING 16           // global h0 ring depth (chunks) per batch
#define H0_DW (CHUNK * 64) // dwords per chunk (64 ticks x 64 packed-f16 dwords)

typedef _Float16 v2h   __attribute__((ext_vector_type(2)));
typedef _Float16 f16x8 __attribute__((ext_vector_type(8)));
typedef float    f32x4 __attribute__((ext_vector_type(4)));

__device__ __forceinline__ unsigned pk2h(float lo, float hi) {
    v2h p;
    p[0] = (_Float16)lo;
    p[1] = (_Float16)hi;
    return __builtin_bit_cast(unsigned, p);
}

#if __has_builtin(__builtin_amdgcn_fdot2)
__device__ __forceinline__ float fdot2a(unsigned a, unsigned b, float c) {
    return __builtin_amdgcn_fdot2(__builtin_bit_cast(v2h, a),
                                  __builtin_bit_cast(v2h, b), c, false);
}
#else
__device__ __forceinline__ float fdot2a(unsigned a, unsigned b, float c) {
    v2h av = __builtin_bit_cast(v2h, a);
    v2h bv = __builtin_bit_cast(v2h, b);
    c += (float)av[0] * (float)bv[0];
    c += (float)av[1] * (float)bv[1];
    return c;
}
#endif

__device__ __forceinline__ float sigm(float x) {
    return 1.0f / (1.0f + __expf(-x));
}
__device__ __forceinline__ float tanh_f(float x) {
    float e = __expf(2.0f * x);
    return 1.0f - 2.0f / (e + 1.0f);
}

__device__ __forceinline__ f32x4 mfma16(f16x8 a, f16x8 b, f32x4 c) {
    return __builtin_amdgcn_mfma_f32_16x16x32_f16(a, b, c, 0, 0, 0);
}

#if __has_builtin(__builtin_amdgcn_mov_dpp)
template <int CTRL>
__device__ __forceinline__ float qperm(float v) {
    int i = __builtin_bit_cast(int, v);
    i = __builtin_amdgcn_mov_dpp(i, CTRL, 0xF, 0xF, true);
    return __builtin_bit_cast(float, i);
}
__device__ __forceinline__ float lane_xor1(float v) { return qperm<0xB1>(v); }
__device__ __forceinline__ float lane_xor2(float v) { return qperm<0x4E>(v); }
#else
__device__ __forceinline__ float lane_xor1(float v) {
    int i = __builtin_amdgcn_ds_swizzle(__builtin_bit_cast(int, v), 0x041F);
    return __builtin_bit_cast(float, i);
}
__device__ __forceinline__ float lane_xor2(float v) {
    int i = __builtin_amdgcn_ds_swizzle(__builtin_bit_cast(int, v), 0x081F);
    return __builtin_bit_cast(float, i);
}
#endif

// ---------------------------------------------------------------------------
// PRODUCER-CONSUMER layer pipeline across blocks (uses 128 CUs, not 64):
//   blocks 0..63   : L0 for batch b      (r5-verified fdot2 phase A; 68 dw VGPR)
//   blocks 64..127 : L1+OUT for batch b-64 (r7/r11-verified MFMA phase B;
//                    128 dw weights pinned AGPR, read natively by MFMA)
// h0 handoff: 16-chunk global ring per batch (16 MB total in d_ws, L3-resident),
// 64-tick chunks, agent-scope acquire/release flags. ALL global ops are
// per-chunk (r4 lesson: per-tick global ops die on barrier vmcnt drains).
// Co-residency: 128 blocks x (8 waves x 256 regs, 48KB LDS) = 1 block/CU,
// 128 <= 256 CUs -> producer & consumer always simultaneously resident.
// Flags memset to 0 on the stream before each launch (graph/replay safe).
// ---------------------------------------------------------------------------
__global__ __launch_bounds__(512, 2)
void lstm2_pc_kernel(const float* __restrict__ x,
                     const float* __restrict__ wih0,
                     const float* __restrict__ whh0,
                     const float* __restrict__ bih0,
                     const float* __restrict__ bhh0,
                     const float* __restrict__ wih1,
                     const float* __restrict__ whh1,
                     const float* __restrict__ bih1,
                     const float* __restrict__ bhh1,
                     const float* __restrict__ wlin,
                     const float* __restrict__ blin,
                     unsigned* __restrict__ h0g,
                     int* __restrict__ flags,
                     float* __restrict__ out)
{
    __shared__ __align__(16) unsigned arena[12288];   // 48 KB, role-dependent layout
    __shared__ float blin_f[F_];

    const int tid = threadIdx.x;
    int* prog = flags;        // producer -> consumer: chunks published
    int* done = flags + 64;   // consumer -> producer: chunks consumed (staged)

    if (blockIdx.x < 64) {
        // =================== PRODUCER: layer 0 ===================
        const int b = blockIdx.x;
        unsigned* x_lds = arena;          // 8192 dwords (32 KB)
        unsigned* ring  = arena + 8192;   // [64][64] dwords (16 KB) h0 ring

        const int h_idx = tid >> 2;
        const int sub   = tid & 3;
        const int growA = (0x3120 >> (sub * 4)) & 0xF;   // {0,2,1,3}[sub]
        const int rowA  = growA * H_ + h_idx;

        const float4* xp = (const float4*)(x + (size_t)b * T_ * F_);
        #pragma unroll
        for (int i = 0; i < 8; ++i) {
            int idx = tid + i * 512;
            float4 v = xp[idx];
            x_lds[idx * 2 + 0] = pk2h(v.x, v.y);
            x_lds[idx * 2 + 1] = pk2h(v.z, v.w);
        }

        unsigned rwih0[4];
        {
            const float4* p = (const float4*)(wih0 + (size_t)rowA * F_);
            float4 v0 = p[0], v1 = p[1];
            rwih0[0] = pk2h(v0.x, v0.y); rwih0[1] = pk2h(v0.z, v0.w);
            rwih0[2] = pk2h(v1.x, v1.y); rwih0[3] = pk2h(v1.z, v1.w);
        }
        unsigned rwhh0[64];
        {
            const float4* p = (const float4*)(whh0 + (size_t)rowA * H_);
            #pragma unroll
            for (int i = 0; i < 32; ++i) {
                float4 v = p[i];
                rwhh0[i * 2 + 0] = pk2h(v.x, v.y);
                rwhh0[i * 2 + 1] = pk2h(v.z, v.w);
            }
        }
        const float bias0 = bih0[rowA] + bhh0[rowA];

        if (tid < 64) ring[63 * 64 + tid] = 0u;   // h0(-1) = 0
        __syncthreads();

        const bool is_g = (sub == 1);
        const bool lo2  = (sub < 2);
        float c0 = 0.0f;

        for (int t = 0; t < T_; ++t) {
            // ---- L0 tick (r5-verified math) ----
            {
                float aa = bias0, ab = 0.0f;
                uint4 xv = *(const uint4*)&x_lds[t * 4];
                aa = fdot2a(rwih0[0], xv.x, aa);
                ab = fdot2a(rwih0[1], xv.y, ab);
                aa = fdot2a(rwih0[2], xv.z, aa);
                ab = fdot2a(rwih0[3], xv.w, ab);
                const unsigned* hr = &ring[((t + 63) & 63) * 64];   // h0(t-1)
                #pragma unroll
                for (int j = 0; j < 16; ++j) {
                    uint4 hv = *(const uint4*)&hr[j * 4];
                    aa = fdot2a(rwhh0[j * 4 + 0], hv.x, aa);
                    ab = fdot2a(rwhh0[j * 4 + 1], hv.y, ab);
                    aa = fdot2a(rwhh0[j * 4 + 2], hv.z, aa);
                    ab = fdot2a(rwhh0[j * 4 + 3], hv.w, ab);
                }
                float a = aa + ab;
                float xin = is_g ? 2.0f * a : a;
                float s   = sigm(xin);
                float act = is_g ? 2.0f * s - 1.0f : s;
                float s1  = lane_xor1(act);
                float p   = lo2 ? act * s1 : (sub == 2 ? act : s1) * c0;
                float cn  = p + lane_xor2(p);
                c0 = cn;
                float oval = (sub == 2) ? s1 : act;
                float h = oval * tanh_f(cn);
                if (sub == 2) ((_Float16*)&ring[(t & 63) * 64])[h_idx] = (_Float16)h;
            }
            __syncthreads();   // slot t visible (single barrier per tick)

            // ---- chunk boundary: publish 64 ticks of h0 ----
            if ((t & 63) == 63) {
                const int c = t >> 6;
                if (c >= GRING) {   // backpressure: don't overwrite unconsumed ring slot
                    while (__hip_atomic_load(&done[b], __ATOMIC_ACQUIRE,
                                             __HIP_MEMORY_SCOPE_AGENT) < c - GRING + 1)
                        __builtin_amdgcn_s_sleep(8);
                    __syncthreads();
                }
                unsigned* dst = h0g + ((size_t)b * GRING + (c & (GRING - 1))) * H0_DW;
                uint4 v0 = *(const uint4*)&ring[tid * 8];
                uint4 v1 = *(const uint4*)&ring[tid * 8 + 4];
                *(uint4*)&dst[tid * 8]     = v0;
                *(uint4*)&dst[tid * 8 + 4] = v1;
                __syncthreads();   // per-wave vmcnt(0) drain -> all stores complete
                if (tid == 0)
                    __hip_atomic_store(&prog[b], c + 1, __ATOMIC_RELEASE,
                                       __HIP_MEMORY_SCOPE_AGENT);
            }
        }
    } else {
        // =================== CONSUMER: layer 1 + OUT ===================
        const int b = blockIdx.x - 64;
        unsigned* h0c    = arena;                 // [64][64] dwords (16 KB)
        unsigned* h1ring = arena + 4096;          // [64][RING_LD] (17 KB)
        unsigned* wlin_p = arena + 4096 + 64 * RING_LD;   // 8 x RING_LD

        const int w   = tid >> 6;
        const int l   = tid & 63;
        const int n   = l & 15;
        const int grp = l >> 4;

        // weights as MFMA B-frags, pinned AGPR (exactly 128 dwords; r11-verified)
        f16x8 wih1f[4][4], whh1f[4][4];
        #pragma unroll
        for (int j = 0; j < 4; ++j) {
            const int row = j * H_ + w * 16 + n;
            #pragma unroll
            for (int s = 0; s < 4; ++s) {
                const float* p1 = wih1 + (size_t)row * H_ + s * 32 + grp * 8;
                const float* p2 = whh1 + (size_t)row * H_ + s * 32 + grp * 8;
                f16x8 f1, f2;
                #pragma unroll
                for (int jj = 0; jj < 8; ++jj) {
                    f1[jj] = (_Float16)p1[jj];
                    f2[jj] = (_Float16)p2[jj];
                }
                wih1f[j][s] = f1;
                whh1f[j][s] = f2;
            }
        }
        #pragma unroll
        for (int j = 0; j < 4; ++j)
            #pragma unroll
            for (int s = 0; s < 4; ++s) {
                asm("" : "+a"(wih1f[j][s]));
                asm("" : "+a"(whh1f[j][s]));
            }

        float bb1[4];
        #pragma unroll
        for (int j = 0; j < 4; ++j) {
            const int row = j * H_ + w * 16 + n;
            bb1[j] = bih1[row] + bhh1[row];
        }
        {
            float2 v = ((const float2*)wlin)[tid];
            wlin_p[(tid >> 6) * RING_LD + (tid & 63)] = pk2h(v.x, v.y);
        }
        if (tid < F_) blin_f[tid] = blin[tid];
        if (tid < 64) h1ring[63 * RING_LD + tid] = 0u;   // h1(-1) = 0
        __syncthreads();

        float c1 = 0.0f;
        const f32x4 Z4 = {0.0f, 0.0f, 0.0f, 0.0f};

        for (int c = 0; c < NCH; ++c) {
            // ---- acquire chunk c of h0 (all threads poll; acquire per wave) ----
            while (__hip_atomic_load(&prog[b], __ATOMIC_ACQUIRE,
                                     __HIP_MEMORY_SCOPE_AGENT) < c + 1)
                __builtin_amdgcn_s_sleep(8);
            const unsigned* src = h0g + ((size_t)b * GRING + (c & (GRING - 1))) * H0_DW;
            uint4 v0 = *(const uint4*)&src[tid * 8];
            uint4 v1 = *(const uint4*)&src[tid * 8 + 4];
            *(uint4*)&h0c[tid * 8]     = v0;
            *(uint4*)&h0c[tid * 8 + 4] = v1;
            __syncthreads();   // staged (loads drained per wave)
            if (tid == 0)
                __hip_atomic_store(&done[b], c + 1, __ATOMIC_RELAXED,
                                   __HIP_MEMORY_SCOPE_AGENT);   // global slot reusable

            // ---- 64 ticks of L1 (r7/r11-verified MFMA phase B) ----
            for (int tk = 0; tk < CHUNK; ++tk) {
                const unsigned* h0r = &h0c[tk * 64];                          // h0(t)
                const unsigned* h1r = &h1ring[((tk + 63) & 63) * RING_LD];    // h1(t-1)
                f32x4 acc[4];
                {
                    f16x8 ah = __builtin_bit_cast(f16x8, *(const uint4*)&h0r[grp * 4]);
                    #pragma unroll
                    for (int j = 0; j < 4; ++j) acc[j] = mfma16(ah, wih1f[j][0], Z4);
                }
                #pragma unroll
                for (int s = 1; s < 4; ++s) {
                    f16x8 ah = __builtin_bit_cast(f16x8,
                                   *(const uint4*)&h0r[s * 16 + grp * 4]);
                    #pragma unroll
                    for (int j = 0; j < 4; ++j) acc[j] = mfma16(ah, wih1f[j][s], acc[j]);
                }
                #pragma unroll
                for (int s = 0; s < 4; ++s) {
                    f16x8 ah = __builtin_bit_cast(f16x8,
                                   *(const uint4*)&h1r[s * 16 + grp * 4]);
                    #pragma unroll
                    for (int j = 0; j < 4; ++j) acc[j] = mfma16(ah, whh1f[j][s], acc[j]);
                }
                float gi = sigm(acc[0][0] + bb1[0]);
                float gf = sigm(acc[1][0] + bb1[1]);
                float gg = tanh_f(acc[2][0] + bb1[2]);
                float go = sigm(acc[3][0] + bb1[3]);
                c1 = gf * c1 + gi * gg;
                float hh = go * tanh_f(c1);
                if (l < 16)
                    ((_Float16*)&h1ring[tk * RING_LD])[w * 16 + l] = (_Float16)hh;
                __syncthreads();   // h1(t) visible (single barrier per tick)
            }

            // ---- OUT burst for this chunk (r5-verified pattern) ----
            {
                const int tick_i = tid >> 3;
                const int fo     = tid & 7;
                const unsigned* hp = &h1ring[tick_i * RING_LD];
                const unsigned* wv = &wlin_p[fo * RING_LD];
                float a = 0.0f;
                #pragma unroll
                for (int j = 0; j < 16; ++j) {
                    uint4 hv = *(const uint4*)&hp[j * 4];
                    uint4 wq = *(const uint4*)&wv[j * 4];
                    a = fdot2a(wq.x, hv.x, a);
                    a = fdot2a(wq.y, hv.y, a);
                    a = fdot2a(wq.z, hv.z, a);
                    a = fdot2a(wq.w, hv.w, a);
                }
                out[(size_t)b * T_ * F_ + (size_t)c * CHUNK * F_ + tid] = a + blin_f[fo];
                // drains at next chunk's staging barrier (32x per sequence)
            }
        }
    }
}

// ===================== Fallback (round-5 verified, 3162 us) =====================
__global__ __launch_bounds__(512, 2)
void lstm2_burst_kernel(const float* __restrict__ x,
                        const float* __restrict__ wih0,
                        const float* __restrict__ whh0,
                        const float* __restrict__ bih0,
                        const float* __restrict__ bhh0,
                        const float* __restrict__ wih1,
                        const float* __restrict__ whh1,
                        const float* __restrict__ bih1,
                        const float* __restrict__ bhh1,
                        const float* __restrict__ wlin,
                        const float* __restrict__ blin,
                        float* __restrict__ out)
{
    __shared__ __align__(16) unsigned x_lds[T_ * F_ / 2];
    __shared__ __align__(16) unsigned h0_p[2][H_ / 2];
    __shared__ __align__(16) unsigned h1_ring[64 * RING_LD];
    __shared__ __align__(16) unsigned wlin_p[F_ * RING_LD];
    __shared__ float blin_f[F_];

    const int tid   = threadIdx.x;
    const int b     = blockIdx.x;
    const int h_idx = tid >> 2;
    const int sub   = tid & 3;
    const int grow  = (0x3120 >> (sub * 4)) & 0xF;
    const int row   = grow * H_ + h_idx;

    const float4* xp = (const float4*)(x + (size_t)b * T_ * F_);
    #pragma unroll
    for (int i = 0; i < 8; ++i) {
        int idx = tid + i * 512;
        float4 v = xp[idx];
        x_lds[idx * 2 + 0] = pk2h(v.x, v.y);
        x_lds[idx * 2 + 1] = pk2h(v.z, v.w);
    }

    unsigned rwih0[4];
    {
        const float4* p = (const float4*)(wih0 + (size_t)row * F_);
        float4 v0 = p[0], v1 = p[1];
        rwih0[0] = pk2h(v0.x, v0.y); rwih0[1] = pk2h(v0.z, v0.w);
        rwih0[2] = pk2h(v1.x, v1.y); rwih0[3] = pk2h(v1.z, v1.w);
    }
    unsigned rwhh0[64], rwih1[64], rwhh1[64];
    {
        const float4* p = (const float4*)(whh0 + (size_t)row * H_);
        #pragma unroll
        for (int i = 0; i < 32; ++i) {
            float4 v = p[i];
            rwhh0[i * 2 + 0] = pk2h(v.x, v.y);
            rwhh0[i * 2 + 1] = pk2h(v.z, v.w);
        }
    }
    {
        const float4* p = (const float4*)(wih1 + (size_t)row * H_);
        #pragma unroll
        for (int i = 0; i < 32; ++i) {
            float4 v = p[i];
            rwih1[i * 2 + 0] = pk2h(v.x, v.y);
            rwih1[i * 2 + 1] = pk2h(v.z, v.w);
        }
    }
    {
        const float4* p = (const float4*)(whh1 + (size_t)row * H_);
        #pragma unroll
        for (int i = 0; i < 32; ++i) {
            float4 v = p[i];
            rwhh1[i * 2 + 0] = pk2h(v.x, v.y);
            rwhh1[i * 2 + 1] = pk2h(v.z, v.w);
        }
    }
    const float bias0 = bih0[row] + bhh0[row];
    const float bias1 = bih1[row] + bhh1[row];

    {
        int r = tid >> 6, c = tid & 63;
        float2 v = ((const float2*)wlin)[r * 64 + c];
        wlin_p[r * RING_LD + c] = pk2h(v.x, v.y);
    }
    if (tid < F_) blin_f[tid] = blin[tid];
    if (tid < H_ / 2) { h0_p[0][tid] = 0u; h0_p[1][tid] = 0u; }
    if (tid < H_ / 2) h1_ring[63 * RING_LD + tid] = 0u;
    __syncthreads();

    const bool is_g = (sub == 1);
    const bool lo2  = (sub < 2);
    float c0 = 0.0f, c1 = 0.0f;

    for (int t = 0; t < T_; ++t) {
        const int rp = (t + 1) & 1;
        const int wp = t & 1;
        {
            float aa = bias0, ab = 0.0f;
            uint4 xv = *(const uint4*)&x_lds[t * 4];
            aa = fdot2a(rwih0[0], xv.x, aa);
            ab = fdot2a(rwih0[1], xv.y, ab);
            aa = fdot2a(rwih0[2], xv.z, aa);
            ab = fdot2a(rwih0[3], xv.w, ab);
            const unsigned* hr = &h0_p[rp][0];
            #pragma unroll
            for (int j = 0; j < 16; ++j) {
                uint4 hv = *(const uint4*)&hr[j * 4];
                aa = fdot2a(rwhh0[j * 4 + 0], hv.x, aa);
                ab = fdot2a(rwhh0[j * 4 + 1], hv.y, ab);
                aa = fdot2a(rwhh0[j * 4 + 2], hv.z, aa);
                ab = fdot2a(rwhh0[j * 4 + 3], hv.w, ab);
            }
            float a = aa + ab;
            float xin = is_g ? 2.0f * a : a;
            float s   = sigm(xin);
            float act = is_g ? 2.0f * s - 1.0f : s;
            float s1  = lane_xor1(act);
            float p   = lo2 ? act * s1 : (sub == 2 ? act : s1) * c0;
            float cn  = p + lane_xor2(p);
            c0 = cn;
            float oval = (sub == 2) ? s1 : act;
            float h = oval * tanh_f(cn);
            if (sub == 2) ((_Float16*)&h0_p[wp][0])[h_idx] = (_Float16)h;
        }
        __syncthreads();
        {
            float aa = bias1, ab = 0.0f, ba = 0.0f, bb = 0.0f;
            const unsigned* h0r = &h0_p[wp][0];
            const unsigned* h1r = &h1_ring[((t + 63) & 63) * RING_LD];
            #pragma unroll
            for (int j = 0; j < 16; ++j) {
                uint4 hv0 = *(const uint4*)&h0r[j * 4];
                uint4 hv1 = *(const uint4*)&h1r[j * 4];
                aa = fdot2a(rwih1[j * 4 + 0], hv0.x, aa);
                ab = fdot2a(rwih1[j * 4 + 1], hv0.y, ab);
                aa = fdot2a(rwih1[j * 4 + 2], hv0.z, aa);
                ab = fdot2a(rwih1[j * 4 + 3], hv0.w, ab);
                ba = fdot2a(rwhh1[j * 4 + 0], hv1.x, ba);
                bb = fdot2a(rwhh1[j * 4 + 1], hv1.y, bb);
                ba = fdot2a(rwhh1[j * 4 + 2], hv1.z, ba);
                bb = fdot2a(rwhh1[j * 4 + 3], hv1.w, bb);
            }
            float a = (aa + ab) + (ba + bb);
            float xin = is_g ? 2.0f * a : a;
            float s   = sigm(xin);
            float act = is_g ? 2.0f * s - 1.0f : s;
            float s1  = lane_xor1(act);
            float p   = lo2 ? act * s1 : (sub == 2 ? act : s1) * c1;
            float cn  = p + lane_xor2(p);
            c1 = cn;
            float oval = (sub == 2) ? s1 : act;
            float h = oval * tanh_f(cn);
            if (sub == 2)
                ((_Float16*)&h1_ring[(t & 63) * RING_LD])[h_idx] = (_Float16)h;
        }
        __syncthreads();
        if ((t & 63) == 63) {
            const int tick_i = tid >> 3;
            const int fo     = tid & 7;
            const unsigned* hp = &h1_ring[tick_i * RING_LD];
            const unsigned* wv = &wlin_p[fo * RING_LD];
            float a = 0.0f;
            #pragma unroll
            for (int j = 0; j < 16; ++j) {
                uint4 hv = *(const uint4*)&hp[j * 4];
                uint4 wq = *(const uint4*)&wv[j * 4];
                a = fdot2a(wq.x, hv.x, a);
                a = fdot2a(wq.y, hv.y, a);
                a = fdot2a(wq.z, hv.z, a);
                a = fdot2a(wq.w, hv.w, a);
            }
            out[(size_t)b * T_ * F_ + (size_t)(t - 63) * F_ + tid] = a + blin_f[fo];
        }
    }
}

extern "C" void kernel_launch(void* const* d_in, const int* in_sizes, int n_in,
                              void* d_out, int out_size, void* d_ws, size_t ws_size,
                              hipStream_t stream) {
    const float* x    = (const float*)d_in[0];
    const float* wih0 = (const float*)d_in[1];
    const float* whh0 = (const float*)d_in[2];
    const float* bih0 = (const float*)d_in[3];
    const float* bhh0 = (const float*)d_in[4];
    const float* wih1 = (const float*)d_in[5];
    const float* whh1 = (const float*)d_in[6];
    const float* bih1 = (const float*)d_in[7];
    const float* bhh1 = (const float*)d_in[8];
    const float* wlin = (const float*)d_in[9];
    const float* blin = (const float*)d_in[10];
    float* out = (float*)d_out;

    const size_t h0_bytes = (size_t)B_ * GRING * H0_DW * sizeof(unsigned);  // 16 MB
    const size_t need = h0_bytes + 512;
    if (d_ws != nullptr && ws_size >= need) {
        unsigned* h0g = (unsigned*)d_ws;
        int* flags = (int*)((char*)d_ws + h0_bytes);   // prog[64], done[64]
        hipMemsetAsync(flags, 0, 512, stream);
        lstm2_pc_kernel<<<dim3(128), dim3(512), 0, stream>>>(
            x, wih0, whh0, bih0, bhh0, wih1, whh1, bih1, bhh1, wlin, blin,
            h0g, flags, out);
    } else {
        lstm2_burst_kernel<<<dim3(B_), dim3(512), 0, stream>>>(
            x, wih0, whh0, bih0, bhh0, wih1, whh1, bih1, bhh1, wlin, blin, out);
    }
}

// Round 13
// 1494.878 us; speedup vs baseline: 2.7758x; 1.2097x over previous
//
#include <hip/hip_runtime.h>

#define B_ 64
#define T_ 2048
#define F_ 8
#define H_ 128
#define RING_LD 68         // padded h1-ring row (dwords)
#define CHUNK 64
#define NCH (T_ / CHUNK)   // 32 chunks
#define GRING 16           // global h0 ring depth (chunks) per batch
#define H0_DW (CHUNK * 64) // dwords per published chunk (dense [64][64])
#define H0C_LD 68          // padded staged-h0 row (dwords)
#define Z_LD 516           // padded zih1 row (f32)

typedef _Float16 v2h   __attribute__((ext_vector_type(2)));
typedef _Float16 f16x8 __attribute__((ext_vector_type(8)));
typedef float    f32x4 __attribute__((ext_vector_type(4)));

__device__ __forceinline__ unsigned pk2h(float lo, float hi) {
    v2h p;
    p[0] = (_Float16)lo;
    p[1] = (_Float16)hi;
    return __builtin_bit_cast(unsigned, p);
}

#if __has_builtin(__builtin_amdgcn_fdot2)
__device__ __forceinline__ float fdot2a(unsigned a, unsigned b, float c) {
    return __builtin_amdgcn_fdot2(__builtin_bit_cast(v2h, a),
                                  __builtin_bit_cast(v2h, b), c, false);
}
#else
__device__ __forceinline__ float fdot2a(unsigned a, unsigned b, float c) {
    v2h av = __builtin_bit_cast(v2h, a);
    v2h bv = __builtin_bit_cast(v2h, b);
    c += (float)av[0] * (float)bv[0];
    c += (float)av[1] * (float)bv[1];
    return c;
}
#endif

__device__ __forceinline__ float sigm(float x) {
    return 1.0f / (1.0f + __expf(-x));
}
__device__ __forceinline__ float tanh_f(float x) {
    float e = __expf(2.0f * x);
    return 1.0f - 2.0f / (e + 1.0f);
}

__device__ __forceinline__ f32x4 mfma16(f16x8 a, f16x8 b, f32x4 c) {
    return __builtin_amdgcn_mfma_f32_16x16x32_f16(a, b, c, 0, 0, 0);
}

#if __has_builtin(__builtin_amdgcn_mov_dpp)
template <int CTRL>
__device__ __forceinline__ float qperm(float v) {
    int i = __builtin_bit_cast(int, v);
    i = __builtin_amdgcn_mov_dpp(i, CTRL, 0xF, 0xF, true);
    return __builtin_bit_cast(float, i);
}
__device__ __forceinline__ float lane_xor1(float v) { return qperm<0xB1>(v); }
__device__ __forceinline__ float lane_xor2(float v) { return qperm<0x4E>(v); }
#else
__device__ __forceinline__ float lane_xor1(float v) {
    int i = __builtin_amdgcn_ds_swizzle(__builtin_bit_cast(int, v), 0x041F);
    return __builtin_bit_cast(float, i);
}
__device__ __forceinline__ float lane_xor2(float v) {
    int i = __builtin_amdgcn_ds_swizzle(__builtin_bit_cast(int, v), 0x081F);
    return __builtin_bit_cast(float, i);
}
#endif

// ---------------------------------------------------------------------------
// r13 = r12 producer-consumer pipeline (verified, 1808us) with both stage
// ticks shortened:
//   PRODUCER: fdot2 L0 unchanged except 4-way accumulator split (dep chain
//     34 -> 17 fdot2).
//   CONSUMER: per-chunk batched GEMM zih1 = Wih1 * h0(t) for 32 ticks at a
//     time (real-A MFMA tiles: A row = lane&15 = tick, D row = (lane>>4)*4+reg
//     = tick [m89-verified], reusing the AGPR-resident wih1f B-frags), stored
//     to padded LDS. Serial tick then = 4 ring reads + 4-deep hh1 MFMA chain
//     + zih1 scalar + activation (was 8 reads + 8-deep chain).
//     No new barrier: each wave writes/reads only its own gate-cols of zih1.
// Handoff protocol (chunk ring in d_ws, agent-scope flags) r12-identical.
// ---------------------------------------------------------------------------
__global__ __launch_bounds__(512, 2)
void lstm2_pc3_kernel(const float* __restrict__ x,
                      const float* __restrict__ wih0,
                      const float* __restrict__ whh0,
                      const float* __restrict__ bih0,
                      const float* __restrict__ bhh0,
                      const float* __restrict__ wih1,
                      const float* __restrict__ whh1,
                      const float* __restrict__ bih1,
                      const float* __restrict__ bhh1,
                      const float* __restrict__ wlin,
                      const float* __restrict__ blin,
                      unsigned* __restrict__ h0g,
                      int* __restrict__ flags,
                      float* __restrict__ out)
{
    // consumer layout: h0c[64][68] | h1ring[64][68] | zih1[32][516] f32 | wlin[8][68]
    // producer layout: x_lds[8192] | ring[64][64]
    __shared__ __align__(16) unsigned arena[25760];   // ~100.6 KB
    __shared__ float blin_f[F_];

    const int tid = threadIdx.x;
    int* prog = flags;        // producer -> consumer: chunks published
    int* done = flags + 64;   // consumer -> producer: chunks consumed

    if (blockIdx.x < 64) {
        // =================== PRODUCER: layer 0 (r12 + 4-way chains) ===================
        const int b = blockIdx.x;
        unsigned* x_lds = arena;          // 8192 dwords
        unsigned* ring  = arena + 8192;   // [64][64] h0 ring

        const int h_idx = tid >> 2;
        const int sub   = tid & 3;
        const int growA = (0x3120 >> (sub * 4)) & 0xF;   // {0,2,1,3}[sub]
        const int rowA  = growA * H_ + h_idx;

        const float4* xp = (const float4*)(x + (size_t)b * T_ * F_);
        #pragma unroll
        for (int i = 0; i < 8; ++i) {
            int idx = tid + i * 512;
            float4 v = xp[idx];
            x_lds[idx * 2 + 0] = pk2h(v.x, v.y);
            x_lds[idx * 2 + 1] = pk2h(v.z, v.w);
        }

        unsigned rwih0[4];
        {
            const float4* p = (const float4*)(wih0 + (size_t)rowA * F_);
            float4 v0 = p[0], v1 = p[1];
            rwih0[0] = pk2h(v0.x, v0.y); rwih0[1] = pk2h(v0.z, v0.w);
            rwih0[2] = pk2h(v1.x, v1.y); rwih0[3] = pk2h(v1.z, v1.w);
        }
        unsigned rwhh0[64];
        {
            const float4* p = (const float4*)(whh0 + (size_t)rowA * H_);
            #pragma unroll
            for (int i = 0; i < 32; ++i) {
                float4 v = p[i];
                rwhh0[i * 2 + 0] = pk2h(v.x, v.y);
                rwhh0[i * 2 + 1] = pk2h(v.z, v.w);
            }
        }
        const float bias0 = bih0[rowA] + bhh0[rowA];

        if (tid < 64) ring[63 * 64 + tid] = 0u;   // h0(-1) = 0
        __syncthreads();

        const bool is_g = (sub == 1);
        const bool lo2  = (sub < 2);
        float c0 = 0.0f;

        for (int t = 0; t < T_; ++t) {
            {
                float aa = bias0, ab = 0.0f, ba = 0.0f, bb = 0.0f;   // 4 chains
                uint4 xv = *(const uint4*)&x_lds[t * 4];
                aa = fdot2a(rwih0[0], xv.x, aa);
                ab = fdot2a(rwih0[1], xv.y, ab);
                ba = fdot2a(rwih0[2], xv.z, ba);
                bb = fdot2a(rwih0[3], xv.w, bb);
                const unsigned* hr = &ring[((t + 63) & 63) * 64];   // h0(t-1)
                #pragma unroll
                for (int j = 0; j < 16; ++j) {
                    uint4 hv = *(const uint4*)&hr[j * 4];
                    aa = fdot2a(rwhh0[j * 4 + 0], hv.x, aa);
                    ab = fdot2a(rwhh0[j * 4 + 1], hv.y, ab);
                    ba = fdot2a(rwhh0[j * 4 + 2], hv.z, ba);
                    bb = fdot2a(rwhh0[j * 4 + 3], hv.w, bb);
                }
                float a = (aa + ab) + (ba + bb);
                float xin = is_g ? 2.0f * a : a;
                float s   = sigm(xin);
                float act = is_g ? 2.0f * s - 1.0f : s;
                float s1  = lane_xor1(act);
                float p   = lo2 ? act * s1 : (sub == 2 ? act : s1) * c0;
                float cn  = p + lane_xor2(p);
                c0 = cn;
                float oval = (sub == 2) ? s1 : act;
                float h = oval * tanh_f(cn);
                if (sub == 2) ((_Float16*)&ring[(t & 63) * 64])[h_idx] = (_Float16)h;
            }
            __syncthreads();

            if ((t & 63) == 63) {
                const int c = t >> 6;
                if (c >= GRING) {
                    while (__hip_atomic_load(&done[b], __ATOMIC_ACQUIRE,
                                             __HIP_MEMORY_SCOPE_AGENT) < c - GRING + 1)
                        __builtin_amdgcn_s_sleep(8);
                    __syncthreads();
                }
                unsigned* dst = h0g + ((size_t)b * GRING + (c & (GRING - 1))) * H0_DW;
                uint4 v0 = *(const uint4*)&ring[tid * 8];
                uint4 v1 = *(const uint4*)&ring[tid * 8 + 4];
                *(uint4*)&dst[tid * 8]     = v0;
                *(uint4*)&dst[tid * 8 + 4] = v1;
                __syncthreads();   // stores drained (vmcnt) before release
                if (tid == 0)
                    __hip_atomic_store(&prog[b], c + 1, __ATOMIC_RELEASE,
                                       __HIP_MEMORY_SCOPE_AGENT);
            }
        }
    } else {
        // =================== CONSUMER: layer 1 + OUT (zih1-GEMM) ===================
        const int b = blockIdx.x - 64;
        unsigned* h0c    = arena;                    // [64][68] staged h0 (padded)
        unsigned* h1ring = arena + 4352;             // [64][68] h1 ring
        float*    zih1   = (float*)(arena + 8704);   // [32][516] f32
        unsigned* wlin_p = arena + 25216;            // [8][68]

        const int w   = tid >> 6;
        const int l   = tid & 63;
        const int n   = l & 15;
        const int grp = l >> 4;

        // weights as MFMA B-frags, pinned AGPR (exactly 128 dwords; r11/r12-verified)
        f16x8 wih1f[4][4], whh1f[4][4];
        #pragma unroll
        for (int j = 0; j < 4; ++j) {
            const int row = j * H_ + w * 16 + n;
            #pragma unroll
            for (int s = 0; s < 4; ++s) {
                const float* p1 = wih1 + (size_t)row * H_ + s * 32 + grp * 8;
                const float* p2 = whh1 + (size_t)row * H_ + s * 32 + grp * 8;
                f16x8 f1, f2;
                #pragma unroll
                for (int jj = 0; jj < 8; ++jj) {
                    f1[jj] = (_Float16)p1[jj];
                    f2[jj] = (_Float16)p2[jj];
                }
                wih1f[j][s] = f1;
                whh1f[j][s] = f2;
            }
        }
        #pragma unroll
        for (int j = 0; j < 4; ++j)
            #pragma unroll
            for (int s = 0; s < 4; ++s) {
                asm("" : "+a"(wih1f[j][s]));
                asm("" : "+a"(whh1f[j][s]));
            }

        float bb1[4];
        #pragma unroll
        for (int j = 0; j < 4; ++j) {
            const int row = j * H_ + w * 16 + n;
            bb1[j] = bih1[row] + bhh1[row];
        }
        {
            float2 v = ((const float2*)wlin)[tid];
            wlin_p[(tid >> 6) * RING_LD + (tid & 63)] = pk2h(v.x, v.y);
        }
        if (tid < F_) blin_f[tid] = blin[tid];
        if (tid < 64) h1ring[63 * RING_LD + tid] = 0u;   // h1(-1) = 0
        __syncthreads();

        float c1 = 0.0f;
        const f32x4 Z4 = {0.0f, 0.0f, 0.0f, 0.0f};

        for (int c = 0; c < NCH; ++c) {
            // ---- acquire + stage chunk c of h0 into padded LDS ----
            while (__hip_atomic_load(&prog[b], __ATOMIC_ACQUIRE,
                                     __HIP_MEMORY_SCOPE_AGENT) < c + 1)
                __builtin_amdgcn_s_sleep(8);
            const unsigned* src = h0g + ((size_t)b * GRING + (c & (GRING - 1))) * H0_DW;
            {
                const int tick = tid >> 3;
                const int off  = (tid & 7) * 8;
                uint4 v0 = *(const uint4*)&src[tick * 64 + off];
                uint4 v1 = *(const uint4*)&src[tick * 64 + off + 4];
                *(uint4*)&h0c[tick * H0C_LD + off]     = v0;
                *(uint4*)&h0c[tick * H0C_LD + off + 4] = v1;
            }
            __syncthreads();   // staged (loads drained)
            if (tid == 0)
                __hip_atomic_store(&done[b], c + 1, __ATOMIC_RELAXED,
                                   __HIP_MEMORY_SCOPE_AGENT);

            for (int half = 0; half < 2; ++half) {
                // ---- batched GEMM: zih1[tk][gate-row] for 32 ticks ----
                // A tile: row = lane&15 = tick-in-tile, k = grp*8+jj (dual of the
                // verified B mapping); D: col = lane&15 (gate n), row = (l>>4)*4+reg
                // = tick-in-tile (m89-verified). Reuses wih1f B-frags from AGPR.
                #pragma unroll
                for (int mt = 0; mt < 2; ++mt) {
                    f32x4 d0 = Z4, d1 = Z4, d2 = Z4, d3 = Z4;
                    const int trow = half * 32 + mt * 16 + n;   // absolute tick in chunk
                    #pragma unroll
                    for (int s = 0; s < 4; ++s) {
                        f16x8 ah = __builtin_bit_cast(
                            f16x8, *(const uint4*)&h0c[trow * H0C_LD + s * 16 + grp * 4]);
                        d0 = mfma16(ah, wih1f[0][s], d0);
                        d1 = mfma16(ah, wih1f[1][s], d1);
                        d2 = mfma16(ah, wih1f[2][s], d2);
                        d3 = mfma16(ah, wih1f[3][s], d3);
                    }
                    const int zr = mt * 16 + grp * 4;   // D rows this lane holds
                    #pragma unroll
                    for (int reg = 0; reg < 4; ++reg) {
                        zih1[(zr + reg) * Z_LD + 0 * H_ + w * 16 + n] = d0[reg];
                        zih1[(zr + reg) * Z_LD + 1 * H_ + w * 16 + n] = d1[reg];
                        zih1[(zr + reg) * Z_LD + 2 * H_ + w * 16 + n] = d2[reg];
                        zih1[(zr + reg) * Z_LD + 3 * H_ + w * 16 + n] = d3[reg];
                    }
                }
                // no barrier: zih1 cols of wave w written and read only by wave w

                // ---- 32 serial ticks: 4-deep hh1 chain + zih1 scalar ----
                for (int tk = 0; tk < 32; ++tk) {
                    const int t  = c * CHUNK + half * 32 + tk;
                    const unsigned* h1r = &h1ring[((t + 63) & 63) * RING_LD];
                    f32x4 a0, a1, a2, a3;
                    {
                        f16x8 ah = __builtin_bit_cast(f16x8, *(const uint4*)&h1r[grp * 4]);
                        a0 = mfma16(ah, whh1f[0][0], Z4);
                        a1 = mfma16(ah, whh1f[1][0], Z4);
                        a2 = mfma16(ah, whh1f[2][0], Z4);
                        a3 = mfma16(ah, whh1f[3][0], Z4);
                    }
                    #pragma unroll
                    for (int s = 1; s < 4; ++s) {
                        f16x8 ah = __builtin_bit_cast(
                            f16x8, *(const uint4*)&h1r[s * 16 + grp * 4]);
                        a0 = mfma16(ah, whh1f[0][s], a0);
                        a1 = mfma16(ah, whh1f[1][s], a1);
                        a2 = mfma16(ah, whh1f[2][s], a2);
                        a3 = mfma16(ah, whh1f[3][s], a3);
                    }
                    const int zbase = (half * 32 + tk) * 0 + tk;   // row within half
                    const float* zp = &zih1[(half * 32 + tk - half * 32) * Z_LD];  // = tk
                    float gi = sigm(a0[0] + zp[0 * H_ + w * 16 + n] + bb1[0]);
                    float gf = sigm(a1[0] + zp[1 * H_ + w * 16 + n] + bb1[1]);
                    float gg = tanh_f(a2[0] + zp[2 * H_ + w * 16 + n] + bb1[2]);
                    float go = sigm(a3[0] + zp[3 * H_ + w * 16 + n] + bb1[3]);
                    (void)zbase;
                    c1 = gf * c1 + gi * gg;
                    float hh = go * tanh_f(c1);
                    if (l < 16)
                        ((_Float16*)&h1ring[(t & 63) * RING_LD])[w * 16 + l] = (_Float16)hh;
                    __syncthreads();   // h1(t) visible
                }
            }

            // ---- OUT burst for this chunk (r12-verified pattern) ----
            {
                const int tick_i = tid >> 3;
                const int fo     = tid & 7;
                const unsigned* hp = &h1ring[tick_i * RING_LD];
                const unsigned* wv = &wlin_p[fo * RING_LD];
                float a = 0.0f;
                #pragma unroll
                for (int j = 0; j < 16; ++j) {
                    uint4 hv = *(const uint4*)&hp[j * 4];
                    uint4 wq = *(const uint4*)&wv[j * 4];
                    a = fdot2a(wq.x, hv.x, a);
                    a = fdot2a(wq.y, hv.y, a);
                    a = fdot2a(wq.z, hv.z, a);
                    a = fdot2a(wq.w, hv.w, a);
                }
                out[(size_t)b * T_ * F_ + (size_t)c * CHUNK * F_ + tid] = a + blin_f[fo];
                // drains at next chunk's staging barrier
            }
        }
    }
}

// ===================== Fallback (round-5 verified, 3162 us) =====================
__global__ __launch_bounds__(512, 2)
void lstm2_burst_kernel(const float* __restrict__ x,
                        const float* __restrict__ wih0,
                        const float* __restrict__ whh0,
                        const float* __restrict__ bih0,
                        const float* __restrict__ bhh0,
                        const float* __restrict__ wih1,
                        const float* __restrict__ whh1,
                        const float* __restrict__ bih1,
                        const float* __restrict__ bhh1,
                        const float* __restrict__ wlin,
                        const float* __restrict__ blin,
                        float* __restrict__ out)
{
    __shared__ __align__(16) unsigned x_lds[T_ * F_ / 2];
    __shared__ __align__(16) unsigned h0_p[2][H_ / 2];
    __shared__ __align__(16) unsigned h1_ring[64 * RING_LD];
    __shared__ __align__(16) unsigned wlin_p[F_ * RING_LD];
    __shared__ float blin_f[F_];

    const int tid   = threadIdx.x;
    const int b     = blockIdx.x;
    const int h_idx = tid >> 2;
    const int sub   = tid & 3;
    const int grow  = (0x3120 >> (sub * 4)) & 0xF;
    const int row   = grow * H_ + h_idx;

    const float4* xp = (const float4*)(x + (size_t)b * T_ * F_);
    #pragma unroll
    for (int i = 0; i < 8; ++i) {
        int idx = tid + i * 512;
        float4 v = xp[idx];
        x_lds[idx * 2 + 0] = pk2h(v.x, v.y);
        x_lds[idx * 2 + 1] = pk2h(v.z, v.w);
    }

    unsigned rwih0[4];
    {
        const float4* p = (const float4*)(wih0 + (size_t)row * F_);
        float4 v0 = p[0], v1 = p[1];
        rwih0[0] = pk2h(v0.x, v0.y); rwih0[1] = pk2h(v0.z, v0.w);
        rwih0[2] = pk2h(v1.x, v1.y); rwih0[3] = pk2h(v1.z, v1.w);
    }
    unsigned rwhh0[64], rwih1[64], rwhh1[64];
    {
        const float4* p = (const float4*)(whh0 + (size_t)row * H_);
        #pragma unroll
        for (int i = 0; i < 32; ++i) {
            float4 v = p[i];
            rwhh0[i * 2 + 0] = pk2h(v.x, v.y);
            rwhh0[i * 2 + 1] = pk2h(v.z, v.w);
        }
    }
    {
        const float4* p = (const float4*)(wih1 + (size_t)row * H_);
        #pragma unroll
        for (int i = 0; i < 32; ++i) {
            float4 v = p[i];
            rwih1[i * 2 + 0] = pk2h(v.x, v.y);
            rwih1[i * 2 + 1] = pk2h(v.z, v.w);
        }
    }
    {
        const float4* p = (const float4*)(whh1 + (size_t)row * H_);
        #pragma unroll
        for (int i = 0; i < 32; ++i) {
            float4 v = p[i];
            rwhh1[i * 2 + 0] = pk2h(v.x, v.y);
            rwhh1[i * 2 + 1] = pk2h(v.z, v.w);
        }
    }
    const float bias0 = bih0[row] + bhh0[row];
    const float bias1 = bih1[row] + bhh1[row];

    {
        int r = tid >> 6, c = tid & 63;
        float2 v = ((const float2*)wlin)[r * 64 + c];
        wlin_p[r * RING_LD + c] = pk2h(v.x, v.y);
    }
    if (tid < F_) blin_f[tid] = blin[tid];
    if (tid < H_ / 2) { h0_p[0][tid] = 0u; h0_p[1][tid] = 0u; }
    if (tid < H_ / 2) h1_ring[63 * RING_LD + tid] = 0u;
    __syncthreads();

    const bool is_g = (sub == 1);
    const bool lo2  = (sub < 2);
    float c0 = 0.0f, c1 = 0.0f;

    for (int t = 0; t < T_; ++t) {
        const int rp = (t + 1) & 1;
        const int wp = t & 1;
        {
            float aa = bias0, ab = 0.0f;
            uint4 xv = *(const uint4*)&x_lds[t * 4];
            aa = fdot2a(rwih0[0], xv.x, aa);
            ab = fdot2a(rwih0[1], xv.y, ab);
            aa = fdot2a(rwih0[2], xv.z, aa);
            ab = fdot2a(rwih0[3], xv.w, ab);
            const unsigned* hr = &h0_p[rp][0];
            #pragma unroll
            for (int j = 0; j < 16; ++j) {
                uint4 hv = *(const uint4*)&hr[j * 4];
                aa = fdot2a(rwhh0[j * 4 + 0], hv.x, aa);
                ab = fdot2a(rwhh0[j * 4 + 1], hv.y, ab);
                aa = fdot2a(rwhh0[j * 4 + 2], hv.z, aa);
                ab = fdot2a(rwhh0[j * 4 + 3], hv.w, ab);
            }
            float a = aa + ab;
            float xin = is_g ? 2.0f * a : a;
            float s   = sigm(xin);
            float act = is_g ? 2.0f * s - 1.0f : s;
            float s1  = lane_xor1(act);
            float p   = lo2 ? act * s1 : (sub == 2 ? act : s1) * c0;
            float cn  = p + lane_xor2(p);
            c0 = cn;
            float oval = (sub == 2) ? s1 : act;
            float h = oval * tanh_f(cn);
            if (sub == 2) ((_Float16*)&h0_p[wp][0])[h_idx] = (_Float16)h;
        }
        __syncthreads();
        {
            float aa = bias1, ab = 0.0f, ba = 0.0f, bb = 0.0f;
            const unsigned* h0r = &h0_p[wp][0];
            const unsigned* h1r = &h1_ring[((t + 63) & 63) * RING_LD];
            #pragma unroll
            for (int j = 0; j < 16; ++j) {
                uint4 hv0 = *(const uint4*)&h0r[j * 4];
                uint4 hv1 = *(const uint4*)&h1r[j * 4];
                aa = fdot2a(rwih1[j * 4 + 0], hv0.x, aa);
                ab = fdot2a(rwih1[j * 4 + 1], hv0.y, ab);
                aa = fdot2a(rwih1[j * 4 + 2], hv0.z, aa);
                ab = fdot2a(rwih1[j * 4 + 3], hv0.w, ab);
                ba = fdot2a(rwhh1[j * 4 + 0], hv1.x, ba);
                bb = fdot2a(rwhh1[j * 4 + 1], hv1.y, bb);
                ba = fdot2a(rwhh1[j * 4 + 2], hv1.z, ba);
                bb = fdot2a(rwhh1[j * 4 + 3], hv1.w, bb);
            }
            float a = (aa + ab) + (ba + bb);
            float xin = is_g ? 2.0f * a : a;
            float s   = sigm(xin);
            float act = is_g ? 2.0f * s - 1.0f : s;
            float s1  = lane_xor1(act);
            float p   = lo2 ? act * s1 : (sub == 2 ? act : s1) * c1;
            float cn  = p + lane_xor2(p);
            c1 = cn;
            float oval = (sub == 2) ? s1 : act;
            float h = oval * tanh_f(cn);
            if (sub == 2)
                ((_Float16*)&h1_ring[(t & 63) * RING_LD])[h_idx] = (_Float16)h;
        }
        __syncthreads();
        if ((t & 63) == 63) {
            const int tick_i = tid >> 3;
            const int fo     = tid & 7;
            const unsigned* hp = &h1_ring[tick_i * RING_LD];
            const unsigned* wv = &wlin_p[fo * RING_LD];
            float a = 0.0f;
            #pragma unroll
            for (int j = 0; j < 16; ++j) {
                uint4 hv = *(const uint4*)&hp[j * 4];
                uint4 wq = *(const uint4*)&wv[j * 4];
                a = fdot2a(wq.x, hv.x, a);
                a = fdot2a(wq.y, hv.y, a);
                a = fdot2a(wq.z, hv.z, a);
                a = fdot2a(wq.w, hv.w, a);
            }
            out[(size_t)b * T_ * F_ + (size_t)(t - 63) * F_ + tid] = a + blin_f[fo];
        }
    }
}

extern "C" void kernel_launch(void* const* d_in, const int* in_sizes, int n_in,
                              void* d_out, int out_size, void* d_ws, size_t ws_size,
                              hipStream_t stream) {
    const float* x    = (const float*)d_in[0];
    const float* wih0 = (const float*)d_in[1];
    const float* whh0 = (const float*)d_in[2];
    const float* bih0 = (const float*)d_in[3];
    const float* bhh0 = (const float*)d_in[4];
    const float* wih1 = (const float*)d_in[5];
    const float* whh1 = (const float*)d_in[6];
    const float* bih1 = (const float*)d_in[7];
    const float* bhh1 = (const float*)d_in[8];
    const float* wlin = (const float*)d_in[9];
    const float* blin = (const float*)d_in[10];
    float* out = (float*)d_out;

    const size_t h0_bytes = (size_t)B_ * GRING * H0_DW * sizeof(unsigned);  // 16 MB
    const size_t need = h0_bytes + 512;
    if (d_ws != nullptr && ws_size >= need) {
        unsigned* h0g = (unsigned*)d_ws;
        int* flags = (int*)((char*)d_ws + h0_bytes);   // prog[64], done[64]
        hipMemsetAsync(flags, 0, 512, stream);
        lstm2_pc3_kernel<<<dim3(128), dim3(512), 0, stream>>>(
            x, wih0, whh0, bih0, bhh0, wih1, whh1, bih1, bhh1, wlin, blin,
            h0g, flags, out);
    } else {
        lstm2_burst_kernel<<<dim3(B_), dim3(512), 0, stream>>>(
            x, wih0, whh0, bih0, bhh0, wih1, whh1, bih1, bhh1, wlin, blin, out);
    }
}